// Round 2
// baseline (358.407 us; speedup 1.0000x reference)
//
#include <hip/hip_runtime.h>

typedef unsigned short ushort_t;
typedef __attribute__((ext_vector_type(8))) __bf16 bf16x8;
typedef __attribute__((ext_vector_type(4))) float f32x4;
typedef __attribute__((ext_vector_type(4))) int i32x4;
typedef __attribute__((ext_vector_type(4))) unsigned short u16x4;

#define BN_EPS 1e-5f
#define APAD 72   // A-tile k-stride (128x64 data, pad to 72: 144B row, 16B-aligned)
#define BPAD 72   // x-halo c-stride
#define EPAD 136  // epilogue [p][c] c-stride (272B row, 16B-aligned)

__device__ __forceinline__ ushort_t f2bf(float f) {
    union { float f; unsigned u; } v; v.f = f;
    unsigned r = v.u + 0x7FFFu + ((v.u >> 16) & 1u);
    return (ushort_t)(r >> 16);
}

// ---------------- router: GAP -> linear -> sigmoid ----------------
__global__ void router_kernel(const float* __restrict__ x, const float* __restrict__ rw,
                              const float* __restrict__ rb, float* __restrict__ r) {
    int b = blockIdx.x, t = threadIdx.x;
    __shared__ float gap[256];
    const float4* xp = (const float4*)(x + ((long)b * 256 + t) * 1024);
    float s = 0.f;
    for (int j = 0; j < 256; ++j) { float4 v = xp[j]; s += v.x + v.y + v.z + v.w; }
    gap[t] = s * (1.f / 1024.f);
    __syncthreads();
    if (t < 8) {
        float a = rb[t];
        for (int c = 0; c < 256; ++c) a += gap[c] * rw[t * 256 + c];
        r[b * 8 + t] = 1.f / (1.f + expf(-a));
    }
}

// ---------------- transpose+cast: x[b][c][p] f32 -> xt[b][p][c] bf16 ----------------
__global__ void transpose_kernel(const float* __restrict__ x, ushort_t* __restrict__ xt) {
    __shared__ float tile[32][33];
    int b = blockIdx.z, c0 = blockIdx.y * 32, p0 = blockIdx.x * 32;
    int tx = threadIdx.x & 31, ty = threadIdx.x >> 5; // ty 0..7
    #pragma unroll
    for (int i = 0; i < 4; ++i) {
        int c = ty + i * 8;
        tile[c][tx] = x[((long)b * 256 + c0 + c) * 1024 + p0 + tx];
    }
    __syncthreads();
    #pragma unroll
    for (int i = 0; i < 4; ++i) {
        int p = ty + i * 8;
        xt[((long)b * 1024 + p0 + p) * 256 + c0 + tx] = f2bf(tile[tx][p]);
    }
}

// ---------------- combine: k[b][pos][o][i] = sum_e r[b,e]*w[e][o][i][pos], bf16 ----------------
__global__ void combine_kernel(const float* __restrict__ w, const float* __restrict__ r,
                               ushort_t* __restrict__ ko) {
    int g = blockIdx.x * 256 + threadIdx.x; // 0..65535 -> (o=g>>8, i=g&255)
    float wv[8][9];
    #pragma unroll
    for (int e = 0; e < 8; ++e)
        #pragma unroll
        for (int p = 0; p < 9; ++p)
            wv[e][p] = w[((long)e * 65536 + g) * 9 + p];
    for (int b = 0; b < 32; ++b) {
        float rv[8];
        #pragma unroll
        for (int e = 0; e < 8; ++e) rv[e] = r[b * 8 + e];
        #pragma unroll
        for (int p = 0; p < 9; ++p) {
            float s = 0.f;
            #pragma unroll
            for (int e = 0; e < 8; ++e) s += rv[e] * wv[e][p];
            ko[((long)(b * 9 + p)) * 65536 + g] = f2bf(s);
        }
    }
}

// ---------------- implicit-GEMM conv 3x3 (pad 1), per-sample weights ----------------
// MODE 0: out = bf16 relu(bn(conv)) written [b][p][c] (transposed via LDS)
// MODE 1: out = f32 relu(bn(conv) + resid) written [b][c][p]
template <int MODE>
__global__ __launch_bounds__(256, 2) void gemm_conv(
    const ushort_t* __restrict__ xin,   // [B][1024][256] bf16
    const ushort_t* __restrict__ kbank, // [B][9][256][256] bf16
    void* __restrict__ outp,
    const float* __restrict__ gam, const float* __restrict__ bet,
    const float* __restrict__ mu, const float* __restrict__ var,
    const float* __restrict__ resid) {
    __shared__ ushort_t smem[23904]; // B-halo: [0,14688) = 6*34*72 ; A: [14688, 23904) = 128*72
    ushort_t* ldsB = smem;
    ushort_t* ldsA = smem + 14688;

    const int t = threadIdx.x;
    const int lane = t & 63;
    const int lane15 = lane & 15;
    const int quad = lane >> 4;
    const int wv = t >> 6;
    const int nt = blockIdx.x; // 0..7  (spatial tile: 4 rows of 32)
    const int mt = blockIdx.y; // 0..1  (c_out half)
    const int b = blockIdx.z;  // 0..31
    const int h0 = nt * 4;
    const int p0 = nt * 128;
    const int mw0 = (wv >> 1) * 64;
    const int nw0 = (wv & 1) * 64;

    f32x4 acc[4][4];
    #pragma unroll
    for (int i = 0; i < 4; ++i)
        #pragma unroll
        for (int j = 0; j < 4; ++j) acc[i][j] = 0.f;

    // zero halo border columns (w'=0 and w'=33) once; never overwritten
    if (t < 96) {
        int hh = t >> 4, side = (t >> 3) & 1, l8 = t & 7;
        i32x4 z = 0;
        *(i32x4*)(&ldsB[(hh * 34 + side * 33) * BPAD + l8 * 8]) = z;
    }

    const long xbase = (long)b * 1024 * 256;
    const long kbase = (long)b * 9 * 65536;

    for (int kc = 0; kc < 4; ++kc) {
        __syncthreads();
        // stage x-halo: 6 rows (h0-1..h0+4) x 32 cols x 64 channels, zeros out of range
        #pragma unroll
        for (int it = 0; it < 6; ++it) {
            int s = t + it * 256;      // 0..1535
            int pi = s >> 3, l8 = s & 7;
            int hh = pi >> 5, ww = pi & 31;
            int hg = h0 + hh - 1;
            i32x4 v = 0;
            if (hg >= 0 && hg < 32)
                v = *(const i32x4*)(xin + xbase + (long)(hg * 32 + ww) * 256 + kc * 64 + l8 * 8);
            *(i32x4*)(&ldsB[(hh * 34 + ww + 1) * BPAD + l8 * 8]) = v;
        }
        for (int pos = 0; pos < 9; ++pos) {
            __syncthreads(); // prev MFMAs done (and, at pos==0, B-halo staged)
            {
                const ushort_t* srcA = kbank + kbase + (long)pos * 65536 + (long)mt * 128 * 256 + kc * 64;
                #pragma unroll
                for (int it = 0; it < 4; ++it) {
                    int s = t + it * 256; // 0..1023
                    int rr = s >> 3, l8 = s & 7;
                    *(i32x4*)(&ldsA[rr * APAD + l8 * 8]) = *(const i32x4*)(srcA + (long)rr * 256 + l8 * 8);
                }
            }
            __syncthreads();
            int dh = pos / 3 - 1, dw = pos % 3 - 1;
            #pragma unroll
            for (int kb = 0; kb < 2; ++kb) {
                int k0 = kb * 32 + quad * 8;
                bf16x8 af[4], bfr[4];
                #pragma unroll
                for (int mf = 0; mf < 4; ++mf)
                    af[mf] = *(const bf16x8*)(&ldsA[(mw0 + mf * 16 + lane15) * APAD + k0]);
                #pragma unroll
                for (int nf = 0; nf < 4; ++nf) {
                    int n = nw0 + nf * 16 + lane15;
                    int hp = (n >> 5) + 1 + dh;
                    int wp = (n & 31) + 1 + dw;
                    bfr[nf] = *(const bf16x8*)(&ldsB[(hp * 34 + wp) * BPAD + k0]);
                }
                #pragma unroll
                for (int mf = 0; mf < 4; ++mf)
                    #pragma unroll
                    for (int nf = 0; nf < 4; ++nf)
                        acc[mf][nf] = __builtin_amdgcn_mfma_f32_16x16x32_bf16(af[mf], bfr[nf], acc[mf][nf], 0, 0, 0);
            }
        }
    }

    // BN scale/shift for this lane's 16 c_out values (reg i -> consecutive c)
    float sc[4][4], sh[4][4];
    #pragma unroll
    for (int mf = 0; mf < 4; ++mf)
        #pragma unroll
        for (int i = 0; i < 4; ++i) {
            int c = mt * 128 + mw0 + mf * 16 + quad * 4 + i;
            float s = gam[c] * rsqrtf(var[c] + BN_EPS);
            sc[mf][i] = s;
            sh[mf][i] = bet[c] - mu[c] * s;
        }

    if (MODE == 0) {
        __syncthreads();
        ushort_t* ldsE = smem; // [128 p][EPAD c]
        #pragma unroll
        for (int mf = 0; mf < 4; ++mf)
            #pragma unroll
            for (int nf = 0; nf < 4; ++nf) {
                int pl = nw0 + nf * 16 + lane15;
                int cb = mw0 + mf * 16 + quad * 4;
                u16x4 pk;
                #pragma unroll
                for (int i = 0; i < 4; ++i) {
                    float v = acc[mf][nf][i] * sc[mf][i] + sh[mf][i];
                    pk[i] = f2bf(fmaxf(v, 0.f));
                }
                *(u16x4*)(&ldsE[pl * EPAD + cb]) = pk;
            }
        __syncthreads();
        ushort_t* op = (ushort_t*)outp;
        #pragma unroll
        for (int it = 0; it < 8; ++it) {
            int s = t + it * 256;
            int row = s >> 4, l16 = s & 15;
            i32x4 v = *(i32x4*)(&ldsE[row * EPAD + l16 * 8]);
            *(i32x4*)(op + ((long)b * 1024 + p0 + row) * 256 + mt * 128 + l16 * 8) = v;
        }
    } else {
        float* op = (float*)outp;
        #pragma unroll
        for (int mf = 0; mf < 4; ++mf)
            #pragma unroll
            for (int nf = 0; nf < 4; ++nf) {
                int p = p0 + nw0 + nf * 16 + lane15;
                #pragma unroll
                for (int i = 0; i < 4; ++i) {
                    int c = mt * 128 + mw0 + mf * 16 + quad * 4 + i;
                    long idx = ((long)b * 256 + c) * 1024 + p;
                    float v = acc[mf][nf][i] * sc[mf][i] + sh[mf][i] + resid[idx];
                    op[idx] = fmaxf(v, 0.f);
                }
            }
    }
}

extern "C" void kernel_launch(void* const* d_in, const int* in_sizes, int n_in,
                              void* d_out, int out_size, void* d_ws, size_t ws_size,
                              hipStream_t stream) {
    const float* x  = (const float*)d_in[0];
    const float* rw = (const float*)d_in[1];
    const float* rb = (const float*)d_in[2];
    const float* w1 = (const float*)d_in[3];
    const float* w2 = (const float*)d_in[4];
    const float* g1 = (const float*)d_in[5];
    const float* b1 = (const float*)d_in[6];
    const float* m1 = (const float*)d_in[7];
    const float* v1 = (const float*)d_in[8];
    const float* g2 = (const float*)d_in[9];
    const float* b2 = (const float*)d_in[10];
    const float* m2 = (const float*)d_in[11];
    const float* v2 = (const float*)d_in[12];

    // Workspace layout (peak 71.5 MB; single k-buffer reused across both layers):
    //   [0,4096)               r       (1 KB used)
    //   [4096, +16 MB)         xt      bf16 [B][1024][256]
    //   [+16 MB, +32 MB)       o1      bf16 [B][1024][256]
    //   [+32 MB, +68 MB)       kbuf    bf16 [B][9][256][256]
    const size_t XT_OFF = 4096;
    const size_t O1_OFF = XT_OFF + (size_t)16777216;
    const size_t KB_OFF = O1_OFF + (size_t)16777216;
    const size_t NEED   = KB_OFF + (size_t)32 * 9 * 65536 * 2;
    if (ws_size < NEED) return; // ws too small: leave output untouched (clean absmax fail as diagnostic)

    char* ws = (char*)d_ws;
    float* r       = (float*)ws;
    ushort_t* xt   = (ushort_t*)(ws + XT_OFF);
    ushort_t* o1   = (ushort_t*)(ws + O1_OFF);
    ushort_t* kbuf = (ushort_t*)(ws + KB_OFF);

    router_kernel<<<32, 256, 0, stream>>>(x, rw, rb, r);
    transpose_kernel<<<dim3(32, 8, 32), 256, 0, stream>>>(x, xt);
    combine_kernel<<<256, 256, 0, stream>>>(w1, r, kbuf);
    gemm_conv<0><<<dim3(8, 2, 32), 256, 0, stream>>>(xt, kbuf, (void*)o1, g1, b1, m1, v1, nullptr);
    combine_kernel<<<256, 256, 0, stream>>>(w2, r, kbuf);
    gemm_conv<1><<<dim3(8, 2, 32), 256, 0, stream>>>(o1, kbuf, d_out, g2, b2, m2, v2, x);
}

// Round 3
// 279.257 us; speedup vs baseline: 1.2834x; 1.2834x over previous
//
#include <hip/hip_runtime.h>

typedef unsigned short ushort_t;
typedef __attribute__((ext_vector_type(8))) __bf16 bf16x8;
typedef __attribute__((ext_vector_type(4))) float f32x4;
typedef __attribute__((ext_vector_type(4))) int i32x4;
typedef __attribute__((ext_vector_type(4))) unsigned short u16x4;

#define BN_EPS 1e-5f
#define EPAD 136  // epilogue [p][c] c-stride (272B row, 16B-aligned)

__device__ __forceinline__ ushort_t f2bf(float f) {
    union { float f; unsigned u; } v; v.f = f;
    unsigned r = v.u + 0x7FFFu + ((v.u >> 16) & 1u);
    return (ushort_t)(r >> 16);
}

// async 16B global->LDS copy; LDS dst must be wave-uniform base (+lane*16 by HW)
__device__ __forceinline__ void async_cp16(const ushort_t* g, ushort_t* l) {
    __builtin_amdgcn_global_load_lds(
        (const __attribute__((address_space(1))) unsigned int*)g,
        (__attribute__((address_space(3))) unsigned int*)l, 16, 0, 0);
}

// ---------------- transpose+cast+GAP: x[b][c][p] f32 -> xt[b][p][c] bf16, partial GAP sums ----------------
__global__ void transpose_gap_kernel(const float* __restrict__ x, ushort_t* __restrict__ xt,
                                     float* __restrict__ gapsum) {
    __shared__ float tile[32][33];
    int b = blockIdx.z, c0 = blockIdx.y * 32, p0 = blockIdx.x * 32;
    int tx = threadIdx.x & 31, ty = threadIdx.x >> 5; // ty 0..7
    float ps[4];
    #pragma unroll
    for (int i = 0; i < 4; ++i) {
        int c = ty + i * 8;
        float v = x[((long)b * 256 + c0 + c) * 1024 + p0 + tx];
        tile[c][tx] = v;
        ps[i] = v;
    }
    #pragma unroll
    for (int off = 16; off; off >>= 1)
        #pragma unroll
        for (int i = 0; i < 4; ++i) ps[i] += __shfl_down(ps[i], off, 32);
    if (tx == 0)
        #pragma unroll
        for (int i = 0; i < 4; ++i) atomicAdd(&gapsum[b * 256 + c0 + ty + i * 8], ps[i]);
    __syncthreads();
    #pragma unroll
    for (int i = 0; i < 4; ++i) {
        int p = ty + i * 8;
        xt[((long)b * 1024 + p0 + p) * 256 + c0 + tx] = f2bf(tile[tx][p]);
    }
}

// ---------------- router linear: r = sigmoid(gap/1024 @ rw^T + rb) ----------------
__global__ void router_linear_kernel(const float* __restrict__ gapsum, const float* __restrict__ rw,
                                     const float* __restrict__ rb, float* __restrict__ r) {
    int t = threadIdx.x, b = t >> 3, e = t & 7;
    float s = 0.f;
    for (int c = 0; c < 256; ++c) s += gapsum[b * 256 + c] * rw[e * 256 + c];
    r[t] = 1.f / (1.f + expf(-(s * (1.f / 1024.f) + rb[e])));
}

// ---------------- combine: k[b][pos][o][i] = sum_e r[b,e]*w[e][o][i][pos], bf16 ----------------
__global__ void combine_kernel(const float* __restrict__ w, const float* __restrict__ r,
                               ushort_t* __restrict__ ko) {
    int g = blockIdx.x * 256 + threadIdx.x; // (o=g>>8, i=g&255)
    int b0 = blockIdx.y * 8;                // 4 b-groups of 8
    float wv[8][9];
    #pragma unroll
    for (int e = 0; e < 8; ++e)
        #pragma unroll
        for (int p = 0; p < 9; ++p)
            wv[e][p] = w[((long)e * 65536 + g) * 9 + p];
    for (int bb = 0; bb < 8; ++bb) {
        int b = b0 + bb;
        float rv[8];
        #pragma unroll
        for (int e = 0; e < 8; ++e) rv[e] = r[b * 8 + e];
        #pragma unroll
        for (int p = 0; p < 9; ++p) {
            float s = 0.f;
            #pragma unroll
            for (int e = 0; e < 8; ++e) s += rv[e] * wv[e][p];
            ko[((long)(b * 9 + p)) * 65536 + g] = f2bf(s);
        }
    }
}

// ---------------- implicit-GEMM conv 3x3 (pad 1), per-sample weights ----------------
// LDS layouts (16B chunks, XOR-swizzled, unpadded, written only by global_load_lds):
//   ldsB: halo [6][34] rows x 8 k-chunks; slot(pi,j) = pi*8 + (j ^ (pi&7))
//   ldsA: 2 x (128 rows x 8 k-chunks); slot(row,j) = row*8 + (j ^ (row&7))
// MODE 0: out = bf16 relu(bn(conv)) [b][p][c];  MODE 1: out = f32 relu(bn(conv)+resid) [b][c][p]
template <int MODE>
__global__ __launch_bounds__(256, 2) void gemm_conv(
    const ushort_t* __restrict__ xin,   // [B][1024][256] bf16
    const ushort_t* __restrict__ kbank, // [B][9][256][256] bf16
    void* __restrict__ outp,
    const float* __restrict__ gam, const float* __restrict__ bet,
    const float* __restrict__ mu, const float* __restrict__ var,
    const float* __restrict__ resid) {
    __shared__ ushort_t smem[29440]; // ldsB: [0,13056) ; ldsA: [13056, 13056+16384)
    ushort_t* ldsB = smem;
    ushort_t* ldsA = smem + 13056;

    const int t = threadIdx.x;
    const int lane = t & 63;
    const int lane15 = lane & 15;
    const int quad = lane >> 4;
    const int wv = t >> 6;
    const int nt = blockIdx.x; // 0..7  (spatial tile: 4 h-rows of 32)
    const int mt = blockIdx.y; // 0..1  (c_out half)
    const int b = blockIdx.z;  // 0..31
    const int h0 = nt * 4;
    const int p0 = nt * 128;
    const int mw0 = (wv >> 1) * 64;
    const int nw0 = (wv & 1) * 64;
    const int wbase = t & ~63;

    f32x4 acc[4][4];
    #pragma unroll
    for (int i = 0; i < 4; ++i)
        #pragma unroll
        for (int j = 0; j < 4; ++j) acc[i][j] = 0.f;

    // pre-zero (once; never overwritten): border cols w'=0,33 for all 6 rows
    if (t < 96) {
        int rix = t >> 3, j = t & 7;
        int pi = (rix >> 1) * 34 + (rix & 1) * 33;
        i32x4 z = 0;
        *(i32x4*)(&ldsB[(pi * 8 + j) * 8]) = z;
    }
    // pre-zero invalid-h interior rows (boundary blocks only; skipped by stageB)
    if (nt == 0) { i32x4 z = 0; *(i32x4*)(&ldsB[(8 + t) * 8]) = z; }                 // hh=0
    if (nt == 7) { i32x4 z = 0; *(i32x4*)(&ldsB[((5 * 34 + 1) * 8 + t) * 8]) = z; }  // hh=5

    const long xbase = (long)b * 1024 * 256;
    const long kbase = (long)b * 9 * 65536;

    auto stageB = [&](int kc) {
        #pragma unroll
        for (int hh = 0; hh < 6; ++hh) {
            int hg = h0 + hh - 1;
            if (hg < 0 || hg >= 32) continue; // block-uniform
            int ww = t >> 3;
            int pi = hh * 34 + 1 + ww;
            int jd = (t & 7) ^ (pi & 7);
            async_cp16(xin + xbase + (long)(hg * 32 + ww) * 256 + kc * 64 + jd * 8,
                       ldsB + ((hh * 34 + 1) * 8 + wbase) * 8);
        }
    };
    auto stageA = [&](int kc, int pos, int buf) {
        const ushort_t* srcA = kbank + kbase + (long)pos * 65536 + (long)mt * 32768 + kc * 64;
        ushort_t* base = ldsA + buf * 8192;
        #pragma unroll
        for (int it = 0; it < 4; ++it) {
            int s = it * 256 + t;
            int row = s >> 3;
            int k8 = (s & 7) ^ (row & 7);
            async_cp16(srcA + (long)row * 256 + k8 * 8, base + (it * 256 + wbase) * 8);
        }
    };

    stageB(0);
    stageA(0, 0, 0);
    __syncthreads();

    int par = 0;
    for (int kc = 0; kc < 4; ++kc) {
        for (int pos = 0; pos < 9; ++pos) {
            if (!(kc == 3 && pos == 8)) {
                int nk = kc, np = pos + 1;
                if (np == 9) { np = 0; ++nk; }
                stageA(nk, np, par ^ 1);
            }
            const int dh = pos / 3 - 1, dw = pos % 3 - 1;
            const ushort_t* ab = ldsA + par * 8192;
            #pragma unroll
            for (int kb = 0; kb < 2; ++kb) {
                int jk = kb * 4 + quad;
                bf16x8 af[4], bfr[4];
                #pragma unroll
                for (int mf = 0; mf < 4; ++mf) {
                    int row = mw0 + mf * 16 + lane15;
                    af[mf] = *(const bf16x8*)(ab + (row * 8 + (jk ^ (row & 7))) * 8);
                }
                #pragma unroll
                for (int nf = 0; nf < 4; ++nf) {
                    int n = nw0 + nf * 16 + lane15;
                    int pi = ((n >> 5) + 1 + dh) * 34 + (n & 31) + 1 + dw;
                    bfr[nf] = *(const bf16x8*)(&ldsB[(pi * 8 + (jk ^ (pi & 7))) * 8]);
                }
                #pragma unroll
                for (int mf = 0; mf < 4; ++mf)
                    #pragma unroll
                    for (int nf = 0; nf < 4; ++nf)
                        acc[mf][nf] = __builtin_amdgcn_mfma_f32_16x16x32_bf16(af[mf], bfr[nf], acc[mf][nf], 0, 0, 0);
            }
            __syncthreads(); // reads of buf[par] & B done; prefetched A arrived
            if (pos == 8 && kc < 3) { stageB(kc + 1); __syncthreads(); }
            par ^= 1;
        }
    }

    // BN scale/shift for this lane's 16 c_out values
    float sc[4][4], sh[4][4];
    #pragma unroll
    for (int mf = 0; mf < 4; ++mf)
        #pragma unroll
        for (int i = 0; i < 4; ++i) {
            int c = mt * 128 + mw0 + mf * 16 + quad * 4 + i;
            float s = gam[c] * rsqrtf(var[c] + BN_EPS);
            sc[mf][i] = s;
            sh[mf][i] = bet[c] - mu[c] * s;
        }

    if (MODE == 0) {
        __syncthreads();
        ushort_t* ldsE = smem; // [128 p][EPAD c]
        #pragma unroll
        for (int mf = 0; mf < 4; ++mf)
            #pragma unroll
            for (int nf = 0; nf < 4; ++nf) {
                int pl = nw0 + nf * 16 + lane15;
                int cb = mw0 + mf * 16 + quad * 4;
                u16x4 pk;
                #pragma unroll
                for (int i = 0; i < 4; ++i) {
                    float v = acc[mf][nf][i] * sc[mf][i] + sh[mf][i];
                    pk[i] = f2bf(fmaxf(v, 0.f));
                }
                *(u16x4*)(&ldsE[pl * EPAD + cb]) = pk;
            }
        __syncthreads();
        ushort_t* op = (ushort_t*)outp;
        #pragma unroll
        for (int it = 0; it < 8; ++it) {
            int s = t + it * 256;
            int row = s >> 4, l16 = s & 15;
            i32x4 v = *(i32x4*)(&ldsE[row * EPAD + l16 * 8]);
            *(i32x4*)(op + ((long)b * 1024 + p0 + row) * 256 + mt * 128 + l16 * 8) = v;
        }
    } else {
        float* op = (float*)outp;
        #pragma unroll
        for (int mf = 0; mf < 4; ++mf)
            #pragma unroll
            for (int nf = 0; nf < 4; ++nf) {
                int p = p0 + nw0 + nf * 16 + lane15;
                #pragma unroll
                for (int i = 0; i < 4; ++i) {
                    int c = mt * 128 + mw0 + mf * 16 + quad * 4 + i;
                    long idx = ((long)b * 256 + c) * 1024 + p;
                    float v = acc[mf][nf][i] * sc[mf][i] + sh[mf][i] + resid[idx];
                    op[idx] = fmaxf(v, 0.f);
                }
            }
    }
}

extern "C" void kernel_launch(void* const* d_in, const int* in_sizes, int n_in,
                              void* d_out, int out_size, void* d_ws, size_t ws_size,
                              hipStream_t stream) {
    const float* x  = (const float*)d_in[0];
    const float* rw = (const float*)d_in[1];
    const float* rb = (const float*)d_in[2];
    const float* w1 = (const float*)d_in[3];
    const float* w2 = (const float*)d_in[4];
    const float* g1 = (const float*)d_in[5];
    const float* b1 = (const float*)d_in[6];
    const float* m1 = (const float*)d_in[7];
    const float* v1 = (const float*)d_in[8];
    const float* g2 = (const float*)d_in[9];
    const float* b2 = (const float*)d_in[10];
    const float* m2 = (const float*)d_in[11];
    const float* v2 = (const float*)d_in[12];

    // ws layout: r [0,1KB) | gapsum [4096, +32KB) | xt | o1 | kbuf (reused for both layers)
    const size_t GAP_OFF = 4096;
    const size_t XT_OFF  = 36864;
    const size_t O1_OFF  = XT_OFF + (size_t)16777216;
    const size_t KB_OFF  = O1_OFF + (size_t)16777216;
    const size_t NEED    = KB_OFF + (size_t)32 * 9 * 65536 * 2;
    if (ws_size < NEED) return;

    char* ws = (char*)d_ws;
    float* r       = (float*)ws;
    float* gapsum  = (float*)(ws + GAP_OFF);
    ushort_t* xt   = (ushort_t*)(ws + XT_OFF);
    ushort_t* o1   = (ushort_t*)(ws + O1_OFF);
    ushort_t* kbuf = (ushort_t*)(ws + KB_OFF);

    hipMemsetAsync(gapsum, 0, 32768, stream);
    transpose_gap_kernel<<<dim3(32, 8, 32), 256, 0, stream>>>(x, xt, gapsum);
    router_linear_kernel<<<1, 256, 0, stream>>>(gapsum, rw, rb, r);
    combine_kernel<<<dim3(256, 4), 256, 0, stream>>>(w1, r, kbuf);
    gemm_conv<0><<<dim3(8, 2, 32), 256, 0, stream>>>(xt, kbuf, (void*)o1, g1, b1, m1, v1, nullptr);
    combine_kernel<<<dim3(256, 4), 256, 0, stream>>>(w2, r, kbuf);
    gemm_conv<1><<<dim3(8, 2, 32), 256, 0, stream>>>(o1, kbuf, d_out, g2, b2, m2, v2, x);
}

// Round 4
// 254.278 us; speedup vs baseline: 1.4095x; 1.0982x over previous
//
#include <hip/hip_runtime.h>

typedef unsigned short ushort_t;
typedef __attribute__((ext_vector_type(8))) __bf16 bf16x8;
typedef __attribute__((ext_vector_type(4))) float f32x4;
typedef __attribute__((ext_vector_type(4))) int i32x4;
typedef __attribute__((ext_vector_type(4))) unsigned short u16x4;

#define BN_EPS 1e-5f
#define EPAD 136  // epilogue [p][c] c-stride (272B row, 16B-aligned)

__device__ __forceinline__ ushort_t f2bf(float f) {
    union { float f; unsigned u; } v; v.f = f;
    unsigned r = v.u + 0x7FFFu + ((v.u >> 16) & 1u);
    return (ushort_t)(r >> 16);
}
__device__ __forceinline__ float bf2f(ushort_t h) {
    union { unsigned u; float f; } v; v.u = ((unsigned)h) << 16; return v.f;
}

// async 16B global->LDS copy; LDS dst is wave-uniform base (+lane*16 by HW)
__device__ __forceinline__ void async_cp16(const ushort_t* g, ushort_t* l) {
    __builtin_amdgcn_global_load_lds(
        (const __attribute__((address_space(1))) unsigned int*)g,
        (__attribute__((address_space(3))) unsigned int*)l, 16, 0, 0);
}

// ---------------- transpose+cast+GAP: x[b][c][p] f32 -> xt[b][p][c] bf16, partial GAP sums ----------------
__global__ void transpose_gap_kernel(const float* __restrict__ x, ushort_t* __restrict__ xt,
                                     float* __restrict__ gapsum) {
    __shared__ float tile[32][33];
    int b = blockIdx.z, c0 = blockIdx.y * 32, p0 = blockIdx.x * 32;
    int tx = threadIdx.x & 31, ty = threadIdx.x >> 5; // ty 0..7
    float ps[4];
    #pragma unroll
    for (int i = 0; i < 4; ++i) {
        int c = ty + i * 8;
        float v = x[((long)b * 256 + c0 + c) * 1024 + p0 + tx];
        tile[c][tx] = v;
        ps[i] = v;
    }
    #pragma unroll
    for (int off = 16; off; off >>= 1)
        #pragma unroll
        for (int i = 0; i < 4; ++i) ps[i] += __shfl_down(ps[i], off, 32);
    if (tx == 0)
        #pragma unroll
        for (int i = 0; i < 4; ++i) atomicAdd(&gapsum[b * 256 + c0 + ty + i * 8], ps[i]);
    __syncthreads();
    #pragma unroll
    for (int i = 0; i < 4; ++i) {
        int p = ty + i * 8;
        xt[((long)b * 1024 + p0 + p) * 256 + c0 + tx] = f2bf(tile[tx][p]);
    }
}

// ---------------- router linear: r = sigmoid(gap/1024 @ rw^T + rb) ----------------
__global__ void router_linear_kernel(const float* __restrict__ gapsum, const float* __restrict__ rw,
                                     const float* __restrict__ rb, float* __restrict__ r) {
    int t = threadIdx.x, b = t >> 3, e = t & 7;
    float s = 0.f;
    for (int c = 0; c < 256; ++c) s += gapsum[b * 256 + c] * rw[e * 256 + c];
    r[t] = 1.f / (1.f + expf(-(s * (1.f / 1024.f) + rb[e])));
}

// ---------------- combine: k[b][pos][o][i] = sum_e r[b,e]*w[e][o][i][pos], bf16 ----------------
__global__ void combine_kernel(const float* __restrict__ w, const float* __restrict__ r,
                               ushort_t* __restrict__ ko) {
    int g = blockIdx.x * 256 + threadIdx.x; // (o=g>>8, i=g&255)
    int b0 = blockIdx.y * 8;                // 4 b-groups of 8
    float wv[8][9];
    #pragma unroll
    for (int e = 0; e < 8; ++e)
        #pragma unroll
        for (int p = 0; p < 9; ++p)
            wv[e][p] = w[((long)e * 65536 + g) * 9 + p];
    for (int bb = 0; bb < 8; ++bb) {
        int b = b0 + bb;
        float rv[8];
        #pragma unroll
        for (int e = 0; e < 8; ++e) rv[e] = r[b * 8 + e];
        #pragma unroll
        for (int p = 0; p < 9; ++p) {
            float s = 0.f;
            #pragma unroll
            for (int e = 0; e < 8; ++e) s += rv[e] * wv[e][p];
            ko[((long)(b * 9 + p)) * 65536 + g] = f2bf(s);
        }
    }
}

// ---------------- implicit-GEMM conv 3x3 (pad 1), per-sample weights ----------------
// Grid: 512 linear blocks, XCD-swizzled: id%8 = b%8 so all 16 (nt,mt) siblings of a
// sample land on one XCD (round-robin id->XCD) => weight/x L2 reuse.
// LDS layouts (16B chunks, XOR-swizzled, unpadded, written only by global_load_lds):
//   ldsB: halo [6][34] rows x 8 k-chunks; slot(pi,j) = pi*8 + (j ^ (pi&7))
//   ldsA: 2 x (128 rows x 8 k-chunks); slot(row,j) = row*8 + (j ^ (row&7))
// MODE 0: out = bf16 relu(bn(conv)) [b][p][c];  MODE 1: out = f32 relu(bn(conv)+resid) [b][c][p]
template <int MODE>
__global__ __launch_bounds__(256, 2) void gemm_conv(
    const ushort_t* __restrict__ xin,   // [B][1024][256] bf16
    const ushort_t* __restrict__ kbank, // [B][9][256][256] bf16
    void* __restrict__ outp,
    const float* __restrict__ gam, const float* __restrict__ bet,
    const float* __restrict__ mu, const float* __restrict__ var,
    const ushort_t* __restrict__ residt) { // [B][1024][256] bf16 (MODE 1 only)
    __shared__ ushort_t smem[29440]; // ldsB: [0,13056) ; ldsA: [13056, 13056+16384)
    ushort_t* ldsB = smem;
    ushort_t* ldsA = smem + 13056;

    const int t = threadIdx.x;
    const int lane = t & 63;
    const int lane15 = lane & 15;
    const int quad = lane >> 4;
    const int wv = t >> 6;
    // XCD swizzle decode
    const int id = blockIdx.x;           // 0..511
    const int q  = id >> 3;              // mt + 2*nt + 16*(b>>3)
    const int mt = q & 1;
    const int nt = (q >> 1) & 7;
    const int b  = (id & 7) + ((q >> 4) << 3);
    const int h0 = nt * 4;
    const int p0 = nt * 128;
    const int mw0 = (wv >> 1) * 64;
    const int nw0 = (wv & 1) * 64;
    const int wbase = t & ~63;

    f32x4 acc[4][4];
    #pragma unroll
    for (int i = 0; i < 4; ++i)
        #pragma unroll
        for (int j = 0; j < 4; ++j) acc[i][j] = 0.f;

    // pre-zero (once; never overwritten): border cols w'=0,33 for all 6 rows
    if (t < 96) {
        int rix = t >> 3, j = t & 7;
        int pi = (rix >> 1) * 34 + (rix & 1) * 33;
        i32x4 z = 0;
        *(i32x4*)(&ldsB[(pi * 8 + j) * 8]) = z;
    }
    // pre-zero invalid-h interior rows (boundary blocks only; skipped by stageB)
    if (nt == 0) { i32x4 z = 0; *(i32x4*)(&ldsB[(8 + t) * 8]) = z; }                 // hh=0
    if (nt == 7) { i32x4 z = 0; *(i32x4*)(&ldsB[((5 * 34 + 1) * 8 + t) * 8]) = z; }  // hh=5

    const long xbase = (long)b * 1024 * 256;
    const long kbase = (long)b * 9 * 65536;

    auto stageB = [&](int kc) {
        #pragma unroll
        for (int hh = 0; hh < 6; ++hh) {
            int hg = h0 + hh - 1;
            if (hg < 0 || hg >= 32) continue; // block-uniform
            int ww = t >> 3;
            int pi = hh * 34 + 1 + ww;
            int jd = (t & 7) ^ (pi & 7);
            async_cp16(xin + xbase + (long)(hg * 32 + ww) * 256 + kc * 64 + jd * 8,
                       ldsB + ((hh * 34 + 1) * 8 + wbase) * 8);
        }
    };
    auto stageA = [&](int kc, int pos, int buf) {
        const ushort_t* srcA = kbank + kbase + (long)pos * 65536 + (long)mt * 32768 + kc * 64;
        ushort_t* base = ldsA + buf * 8192;
        #pragma unroll
        for (int it = 0; it < 4; ++it) {
            int s = it * 256 + t;
            int row = s >> 3;
            int k8 = (s & 7) ^ (row & 7);
            async_cp16(srcA + (long)row * 256 + k8 * 8, base + (it * 256 + wbase) * 8);
        }
    };

    stageB(0);
    stageA(0, 0, 0);
    __syncthreads();

    int par = 0;
    for (int kc = 0; kc < 4; ++kc) {
        for (int pos = 0; pos < 9; ++pos) {
            if (!(kc == 3 && pos == 8)) {
                int nk = kc, np = pos + 1;
                if (np == 9) { np = 0; ++nk; }
                stageA(nk, np, par ^ 1);
            }
            const int dh = pos / 3 - 1, dw = pos % 3 - 1;
            const ushort_t* ab = ldsA + par * 8192;
            #pragma unroll
            for (int kb = 0; kb < 2; ++kb) {
                int jk = kb * 4 + quad;
                bf16x8 af[4], bfr[4];
                #pragma unroll
                for (int mf = 0; mf < 4; ++mf) {
                    int row = mw0 + mf * 16 + lane15;
                    af[mf] = *(const bf16x8*)(ab + (row * 8 + (jk ^ (row & 7))) * 8);
                }
                #pragma unroll
                for (int nf = 0; nf < 4; ++nf) {
                    int n = nw0 + nf * 16 + lane15;
                    int pi = ((n >> 5) + 1 + dh) * 34 + (n & 31) + 1 + dw;
                    bfr[nf] = *(const bf16x8*)(&ldsB[(pi * 8 + (jk ^ (pi & 7))) * 8]);
                }
                #pragma unroll
                for (int mf = 0; mf < 4; ++mf)
                    #pragma unroll
                    for (int nf = 0; nf < 4; ++nf)
                        acc[mf][nf] = __builtin_amdgcn_mfma_f32_16x16x32_bf16(af[mf], bfr[nf], acc[mf][nf], 0, 0, 0);
            }
            __syncthreads(); // reads of buf[par] & B done; prefetched A arrived
            if (pos == 8 && kc < 3) { stageB(kc + 1); __syncthreads(); }
            par ^= 1;
        }
    }

    // residual prefetch (MODE 1): bf16 from xt, 4 consecutive c per acc frag
    u16x4 rres[4][4];
    if (MODE == 1) {
        #pragma unroll
        for (int mf = 0; mf < 4; ++mf)
            #pragma unroll
            for (int nf = 0; nf < 4; ++nf) {
                int p = p0 + nw0 + nf * 16 + lane15;
                int cb = mt * 128 + mw0 + mf * 16 + quad * 4;
                rres[mf][nf] = *(const u16x4*)(residt + ((long)b * 1024 + p) * 256 + cb);
            }
    }

    // BN scale/shift for this lane's 16 c_out values
    float sc[4][4], sh[4][4];
    #pragma unroll
    for (int mf = 0; mf < 4; ++mf)
        #pragma unroll
        for (int i = 0; i < 4; ++i) {
            int c = mt * 128 + mw0 + mf * 16 + quad * 4 + i;
            float s = gam[c] * rsqrtf(var[c] + BN_EPS);
            sc[mf][i] = s;
            sh[mf][i] = bet[c] - mu[c] * s;
        }

    if (MODE == 0) {
        __syncthreads();
        ushort_t* ldsE = smem; // [128 p][EPAD c]
        #pragma unroll
        for (int mf = 0; mf < 4; ++mf)
            #pragma unroll
            for (int nf = 0; nf < 4; ++nf) {
                int pl = nw0 + nf * 16 + lane15;
                int cb = mw0 + mf * 16 + quad * 4;
                u16x4 pk;
                #pragma unroll
                for (int i = 0; i < 4; ++i) {
                    float v = acc[mf][nf][i] * sc[mf][i] + sh[mf][i];
                    pk[i] = f2bf(fmaxf(v, 0.f));
                }
                *(u16x4*)(&ldsE[pl * EPAD + cb]) = pk;
            }
        __syncthreads();
        ushort_t* op = (ushort_t*)outp;
        #pragma unroll
        for (int it = 0; it < 8; ++it) {
            int s = t + it * 256;
            int row = s >> 4, l16 = s & 15;
            i32x4 v = *(i32x4*)(&ldsE[row * EPAD + l16 * 8]);
            *(i32x4*)(op + ((long)b * 1024 + p0 + row) * 256 + mt * 128 + l16 * 8) = v;
        }
    } else {
        float* op = (float*)outp;
        #pragma unroll
        for (int mf = 0; mf < 4; ++mf)
            #pragma unroll
            for (int nf = 0; nf < 4; ++nf) {
                int p = p0 + nw0 + nf * 16 + lane15;
                #pragma unroll
                for (int i = 0; i < 4; ++i) {
                    int c = mt * 128 + mw0 + mf * 16 + quad * 4 + i;
                    float v = acc[mf][nf][i] * sc[mf][i] + sh[mf][i] + bf2f(rres[mf][nf][i]);
                    op[((long)b * 256 + c) * 1024 + p] = fmaxf(v, 0.f);
                }
            }
    }
}

extern "C" void kernel_launch(void* const* d_in, const int* in_sizes, int n_in,
                              void* d_out, int out_size, void* d_ws, size_t ws_size,
                              hipStream_t stream) {
    const float* x  = (const float*)d_in[0];
    const float* rw = (const float*)d_in[1];
    const float* rb = (const float*)d_in[2];
    const float* w1 = (const float*)d_in[3];
    const float* w2 = (const float*)d_in[4];
    const float* g1 = (const float*)d_in[5];
    const float* b1 = (const float*)d_in[6];
    const float* m1 = (const float*)d_in[7];
    const float* v1 = (const float*)d_in[8];
    const float* g2 = (const float*)d_in[9];
    const float* b2 = (const float*)d_in[10];
    const float* m2 = (const float*)d_in[11];
    const float* v2 = (const float*)d_in[12];

    // ws layout: r [0,1KB) | gapsum [4096, +32KB) | xt | o1 | kbuf (reused for both layers)
    const size_t GAP_OFF = 4096;
    const size_t XT_OFF  = 36864;
    const size_t O1_OFF  = XT_OFF + (size_t)16777216;
    const size_t KB_OFF  = O1_OFF + (size_t)16777216;
    const size_t NEED    = KB_OFF + (size_t)32 * 9 * 65536 * 2;
    if (ws_size < NEED) return;

    char* ws = (char*)d_ws;
    float* r       = (float*)ws;
    float* gapsum  = (float*)(ws + GAP_OFF);
    ushort_t* xt   = (ushort_t*)(ws + XT_OFF);
    ushort_t* o1   = (ushort_t*)(ws + O1_OFF);
    ushort_t* kbuf = (ushort_t*)(ws + KB_OFF);

    hipMemsetAsync(gapsum, 0, 32768, stream);
    transpose_gap_kernel<<<dim3(32, 8, 32), 256, 0, stream>>>(x, xt, gapsum);
    router_linear_kernel<<<1, 256, 0, stream>>>(gapsum, rw, rb, r);
    combine_kernel<<<dim3(256, 4), 256, 0, stream>>>(w1, r, kbuf);
    gemm_conv<0><<<512, 256, 0, stream>>>(xt, kbuf, (void*)o1, g1, b1, m1, v1, nullptr);
    combine_kernel<<<dim3(256, 4), 256, 0, stream>>>(w2, r, kbuf);
    gemm_conv<1><<<512, 256, 0, stream>>>(o1, kbuf, d_out, g2, b2, m2, v2, xt);
}